// Round 3
// baseline (109.613 us; speedup 1.0000x reference)
//
#include <hip/hip_runtime.h>
#include <hip/hip_bf16.h>
#include <hip/hip_fp16.h>

#define NB 8
#define NS 1024
#define NH 8
#define CHUNK 32                      // s-values per block
#define NPAD 1028                     // 1024 + 4 pad

static __device__ __forceinline__ float bfbits2f(unsigned short u) {
    union { unsigned int i; float f; } v;
    v.i = ((unsigned int)u) << 16;
    return v.f;
}

// Detect whether x is stored as float32 (vs bf16). bf16 N(0,1): every sampled
// exponent field is sane. f32: even ushorts are uniform mantissa halves
// (~17% sane). Uniform verdict across all threads/blocks.
static __device__ __forceinline__ bool detect_f32(const void* x) {
    const unsigned short* u = (const unsigned short*)x;
    int sane = 0;
#pragma unroll
    for (int i = 0; i < 32; ++i) {
        unsigned int e = (u[2 * i] >> 7) & 0xFF;
        sane += (e >= 0x60 && e <= 0x8A) ? 1 : 0;
    }
    return sane < 24;
}

static __device__ __forceinline__ void load_row8(const void* base, size_t off,
                                                 bool f32in, float a[8]) {
    if (f32in) {
        const float4* p = (const float4*)((const float*)base + off);
        float4 lo = p[0], hi = p[1];
        a[0] = lo.x; a[1] = lo.y; a[2] = lo.z; a[3] = lo.w;
        a[4] = hi.x; a[5] = hi.y; a[6] = hi.z; a[7] = hi.w;
    } else {
        const ushort4* p = (const ushort4*)((const unsigned short*)base + off);
        ushort4 lo = p[0], hi = p[1];
        a[0] = bfbits2f(lo.x); a[1] = bfbits2f(lo.y);
        a[2] = bfbits2f(lo.z); a[3] = bfbits2f(lo.w);
        a[4] = bfbits2f(hi.x); a[5] = bfbits2f(hi.y);
        a[6] = bfbits2f(hi.z); a[7] = bfbits2f(hi.w);
    }
}

// Quantum layer collapsed analytically: with c_j = cos(x_j + th_j),
//   meas[0]    = c1*c2*...*c7
//   meas[w>=1] = c0*c1*...*cw
// (CNOT chain = basis permutation: bit_w -> XOR_{j<=w} b_j, bit_0 -> XOR_{j>=1} b_j;
//  expectation of (-1)^XOR of independent bits = product of cos(x_j+th_j).)
// q = meas[0:3], k = meas[3:6], v = meas[6:8]; flash attention (scores bounded
// in [-0.375,0.375] -> no max subtraction); then 16->64 projection.
__global__ __launch_bounds__(256) void fused_kernel(const void* __restrict__ x,
                                                    const void* __restrict__ theta,
                                                    const void* __restrict__ W,
                                                    const void* __restrict__ bias,
                                                    float* __restrict__ out) {
    __shared__ __half2 kvA[NH][NPAD];       // (k0,k1) = (m3,m4)
    __shared__ __half2 kvB[NH][NPAD];       // (k2,v0) = (m5,m6)
    __shared__ __half  kvC[NH][NPAD];       // v1 = m7
    __shared__ float   att[CHUNK][17];      // +1 pad
    __shared__ float   Wt[16][64];          // Wt[j][e] = W[e][j]
    __shared__ float   bl[64];

    const int tid = threadIdx.x;
    const int b = blockIdx.x >> 5;          // 32 chunks per batch
    const int chunk = blockIdx.x & 31;

    const bool f32in = detect_f32(x);

    float th[8];
#pragma unroll
    for (int j = 0; j < 8; ++j)
        th[j] = f32in ? ((const float*)theta)[j]
                      : bfbits2f(((const unsigned short*)theta)[j]);

    // ---- stage W^T and bias ----
    for (int i = tid; i < 1024; i += 256) {
        int e = i >> 4, j = i & 15;
        Wt[j][e] = f32in ? ((const float*)W)[i]
                         : bfbits2f(((const unsigned short*)W)[i]);
    }
    if (tid < 64)
        bl[tid] = f32in ? ((const float*)bias)[tid]
                        : bfbits2f(((const unsigned short*)bias)[tid]);

    // ---- stage k/v for all (h, t) of this batch ----
    for (int i = 0; i < 32; ++i) {
        int r = tid + (i << 8);             // h fastest -> coalesced x reads
        int h = r & 7, t = r >> 3;
        float a[8];
        load_row8(x, (((size_t)(b * NS + t)) << 6) + h * 8, f32in, a);
        float c0 = __cosf(a[0] + th[0]);
        float c1 = __cosf(a[1] + th[1]);
        float c2 = __cosf(a[2] + th[2]);
        float c3 = __cosf(a[3] + th[3]);
        float c4 = __cosf(a[4] + th[4]);
        float c5 = __cosf(a[5] + th[5]);
        float c6 = __cosf(a[6] + th[6]);
        float c7 = __cosf(a[7] + th[7]);
        float m3 = ((c0 * c1) * c2) * c3;
        float m4 = m3 * c4;
        float m5 = m4 * c5;
        float m6 = m5 * c6;
        float m7 = m6 * c7;
        kvA[h][t] = __floats2half2_rn(m3, m4);
        kvB[h][t] = __floats2half2_rn(m5, m6);
        kvC[h][t] = __float2half_rn(m7);
    }
    __syncthreads();

    // ---- attention: thread -> (h = tid>>5, s_local = tid&31) ----
    {
        const int h = tid >> 5;
        const int sl = tid & 31;
        const int sg = chunk * CHUNK + sl;
        float a[8];
        load_row8(x, (((size_t)(b * NS + sg)) << 6) + h * 8, f32in, a);
        float c0 = __cosf(a[0] + th[0]);
        float c1 = __cosf(a[1] + th[1]);
        float c2 = __cosf(a[2] + th[2]);
        float c3 = __cosf(a[3] + th[3]);
        float c4 = __cosf(a[4] + th[4]);
        float c5 = __cosf(a[5] + th[5]);
        float c6 = __cosf(a[6] + th[6]);
        float c7 = __cosf(a[7] + th[7]);
        float m1 = c0 * c1;
        float m2 = m1 * c2;
        float m0 = ((c1 * c2) * (c3 * c4)) * ((c5 * c6) * c7);
        float q0 = m0 * 0.125f, q1 = m1 * 0.125f, q2 = m2 * 0.125f;

        float sum = 0.f, a0 = 0.f, a1 = 0.f;
#pragma unroll 4
        for (int t = 0; t < NS; ++t) {
            float2 kk = __half22float2(kvA[h][t]);   // (k0,k1) broadcast
            float2 kv = __half22float2(kvB[h][t]);   // (k2,v0)
            float v1 = __half2float(kvC[h][t]);
            float sc = q0 * kk.x + q1 * kk.y + q2 * kv.x;
            float e = __expf(sc);
            sum += e;
            a0 += e * kv.y;
            a1 += e * v1;
        }
        float inv = 1.0f / sum;
        att[sl][h * 2] = a0 * inv;
        att[sl][h * 2 + 1] = a1 * inv;
    }
    __syncthreads();

    // ---- projection: (CHUNK,16) @ W^T + bias -> (CHUNK,64) f32 ----
    {
        const int e = tid & 63;
        const int rr = tid >> 6;
#pragma unroll
        for (int i = 0; i < 8; ++i) {
            int sl = rr * 8 + i;
            float acc = bl[e];
#pragma unroll
            for (int j = 0; j < 16; ++j)
                acc += att[sl][j] * Wt[j][e];
            int sg = chunk * CHUNK + sl;
            out[(((size_t)(b * NS + sg)) << 6) + e] = acc;
        }
    }
}

extern "C" void kernel_launch(void* const* d_in, const int* in_sizes, int n_in,
                              void* d_out, int out_size, void* d_ws, size_t ws_size,
                              hipStream_t stream) {
    const void* x     = d_in[0];
    const void* theta = d_in[1];
    const void* W     = d_in[2];
    const void* bias  = d_in[3];
    float* out = (float*)d_out;

    fused_kernel<<<dim3(NB * (NS / CHUNK)), dim3(256), 0, stream>>>(x, theta, W, bias, out);
}

// Round 4
// 89.123 us; speedup vs baseline: 1.2299x; 1.2299x over previous
//
#include <hip/hip_runtime.h>
#include <hip/hip_bf16.h>
#include <hip/hip_fp16.h>

#define NB 8
#define NS 1024
#define NH 8
#define TSLICE 8                  // t-loop split per s
#define SPB 32                    // s-values per attn block

// ---------------------------------------------------------------------------
// Quantum layer collapsed analytically: with c_j = cos(x_j + th_j),
//   meas[0]    = c1*c2*...*c7
//   meas[w>=1] = c0*c1*...*cw
// (CNOT chain = basis permutation; E[(-1)^XOR of independent bits] = product.)
// q = meas[0:3]/8, k = meas[3:6], v = meas[6:8]; scores in [-0.375,0.375] so
// softmax needs no max subtraction. Verified vs np reference in R3.
// ---------------------------------------------------------------------------

// ws layout (floats):
//   q4 : float4[NB*NH*NS]  (q0,q1,q2,_)  prescaled by 0.125
//   kv4: float4[NB*NH*NS]  (k0,k1,k2,v0)
//   v1 : float [NB*NH*NS]
//   att: float [NB*NS*16]
#define Q4_OFF  0
#define KV4_OFF (NB * NH * NS)                 // in float4 units
#define V1_OFF  (2 * NB * NH * NS * 4)         // in float units
#define ATT_OFF (V1_OFF + NB * NH * NS)
#define WS_FLOATS (ATT_OFF + NB * NS * 16)

__global__ __launch_bounds__(256) void meas_kernel(const float* __restrict__ x,
                                                   const float* __restrict__ theta,
                                                   float4* __restrict__ q4,
                                                   float4* __restrict__ kv4,
                                                   float* __restrict__ v1) {
    int r = blockIdx.x * 256 + threadIdx.x;     // (b*S+s)*8 + h, h fastest
    int h = r & 7;
    int bs = r >> 3;
    int s = bs & (NS - 1), b = bs >> 10;

    float th[8];
#pragma unroll
    for (int j = 0; j < 8; ++j) th[j] = theta[j];

    const float4* xp = (const float4*)(x + (((size_t)bs) << 6) + h * 8);
    float4 lo = xp[0], hi = xp[1];

    float c0 = __cosf(lo.x + th[0]);
    float c1 = __cosf(lo.y + th[1]);
    float c2 = __cosf(lo.z + th[2]);
    float c3 = __cosf(lo.w + th[3]);
    float c4 = __cosf(hi.x + th[4]);
    float c5 = __cosf(hi.y + th[5]);
    float c6 = __cosf(hi.z + th[6]);
    float c7 = __cosf(hi.w + th[7]);

    float m1 = c0 * c1;
    float m2 = m1 * c2;
    float m3 = m2 * c3;
    float m4 = m3 * c4;
    float m5 = m4 * c5;
    float m6 = m5 * c6;
    float m7 = m6 * c7;
    float m0 = ((c1 * c2) * (c3 * c4)) * ((c5 * c6) * c7);

    int o = (b * NH + h) * NS + s;
    q4[o]  = make_float4(m0 * 0.125f, m1 * 0.125f, m2 * 0.125f, 0.f);
    kv4[o] = make_float4(m3, m4, m5, m6);
    v1[o]  = m7;
}

__global__ __launch_bounds__(256) void attn_kernel(const float4* __restrict__ q4,
                                                   const float4* __restrict__ kv4,
                                                   const float* __restrict__ v1g,
                                                   float* __restrict__ att) {
    __shared__ float4 kvl[NS];                       // 16 KB
    __shared__ float  v1l[NS];                       // 4 KB
    __shared__ float  redS[TSLICE][SPB + 1];         // 3 x 1.03 KB
    __shared__ float  redA[TSLICE][SPB + 1];
    __shared__ float  redB[TSLICE][SPB + 1];

    const int tid = threadIdx.x;
    const int bh = blockIdx.x >> 5;                  // b*8+h
    const int chunk = blockIdx.x & 31;

    const float4* kvp = kv4 + (size_t)bh * NS;
    const float*  v1p = v1g + (size_t)bh * NS;
    for (int t = tid; t < NS; t += 256) { kvl[t] = kvp[t]; v1l[t] = v1p[t]; }
    __syncthreads();

    const int sl = tid & 31, slice = tid >> 5;
    const int s = chunk * SPB + sl;
    float4 q = q4[(size_t)bh * NS + s];

    float sum = 0.f, a0 = 0.f, a1 = 0.f;
    const int t0 = slice * (NS / TSLICE);
#pragma unroll 4
    for (int i = 0; i < NS / TSLICE; ++i) {
        int t = t0 + i;
        float4 kv = kvl[t];                          // broadcast (2 addrs/wave)
        float e = __expf(q.x * kv.x + q.y * kv.y + q.z * kv.z);
        sum += e;
        a0 += e * kv.w;
        a1 += e * v1l[t];
    }
    redS[slice][sl] = sum;
    redA[slice][sl] = a0;
    redB[slice][sl] = a1;
    __syncthreads();

    if (tid < SPB) {
        float S = 0.f, A = 0.f, B2 = 0.f;
#pragma unroll
        for (int k = 0; k < TSLICE; ++k) {
            S += redS[k][tid]; A += redA[k][tid]; B2 += redB[k][tid];
        }
        float inv = 1.0f / S;
        int b = bh >> 3, h = bh & 7;
        int s2 = chunk * SPB + tid;
        float* o = att + ((size_t)(b * NS + s2) * 16) + h * 2;
        o[0] = A * inv;
        o[1] = B2 * inv;
    }
}

__global__ __launch_bounds__(256) void proj_kernel(const float* __restrict__ att,
                                                   const float* __restrict__ W,
                                                   const float* __restrict__ bias,
                                                   float* __restrict__ out) {
    __shared__ float Wt[16][64];                     // Wt[j][e] = W[e*16+j]
    __shared__ float bl[64];
    __shared__ float rows[4][16];
    int tid = threadIdx.x;
    for (int i = tid; i < 1024; i += 256) Wt[i & 15][i >> 4] = W[i];
    if (tid < 64) bl[tid] = bias[tid];
    int rbase = blockIdx.x * 4;
    if (tid < 64) rows[tid >> 4][tid & 15] = att[(size_t)rbase * 16 + tid];
    __syncthreads();

    int row = tid >> 6, e = tid & 63;
    float acc = bl[e];
#pragma unroll
    for (int j = 0; j < 16; ++j)
        acc += rows[row][j] * Wt[j][e];
    out[(((size_t)(rbase + row)) << 6) + e] = acc;
}

// ---------------------------------------------------------------------------
// Fallback (R3, proven): fully fused, no workspace. Used only if ws too small.
// ---------------------------------------------------------------------------
#define NPAD 1028
__global__ __launch_bounds__(256) void fused_kernel(const float* __restrict__ x,
                                                    const float* __restrict__ theta,
                                                    const float* __restrict__ W,
                                                    const float* __restrict__ bias,
                                                    float* __restrict__ out) {
    __shared__ __half2 kvA[NH][NPAD];
    __shared__ __half2 kvB[NH][NPAD];
    __shared__ __half  kvC[NH][NPAD];
    __shared__ float   attl[SPB][17];
    __shared__ float   Wt[16][64];
    __shared__ float   bl[64];

    const int tid = threadIdx.x;
    const int b = blockIdx.x >> 5;
    const int chunk = blockIdx.x & 31;

    float th[8];
#pragma unroll
    for (int j = 0; j < 8; ++j) th[j] = theta[j];

    for (int i = tid; i < 1024; i += 256) Wt[i & 15][i >> 4] = W[i];
    if (tid < 64) bl[tid] = bias[tid];

    for (int i = 0; i < 32; ++i) {
        int r = tid + (i << 8);
        int h = r & 7, t = r >> 3;
        const float4* xp = (const float4*)(x + (((size_t)(b * NS + t)) << 6) + h * 8);
        float4 lo = xp[0], hi = xp[1];
        float c0 = __cosf(lo.x + th[0]);
        float c1 = __cosf(lo.y + th[1]);
        float c2 = __cosf(lo.z + th[2]);
        float c3 = __cosf(lo.w + th[3]);
        float c4 = __cosf(hi.x + th[4]);
        float c5 = __cosf(hi.y + th[5]);
        float c6 = __cosf(hi.z + th[6]);
        float c7 = __cosf(hi.w + th[7]);
        float m3 = ((c0 * c1) * c2) * c3;
        float m4 = m3 * c4;
        float m5 = m4 * c5;
        float m6 = m5 * c6;
        float m7 = m6 * c7;
        kvA[h][t] = __floats2half2_rn(m3, m4);
        kvB[h][t] = __floats2half2_rn(m5, m6);
        kvC[h][t] = __float2half_rn(m7);
    }
    __syncthreads();

    {
        const int h = tid >> 5;
        const int sl = tid & 31;
        const int sg = chunk * SPB + sl;
        const float4* xp = (const float4*)(x + (((size_t)(b * NS + sg)) << 6) + h * 8);
        float4 lo = xp[0], hi = xp[1];
        float c0 = __cosf(lo.x + th[0]);
        float c1 = __cosf(lo.y + th[1]);
        float c2 = __cosf(lo.z + th[2]);
        float c3 = __cosf(lo.w + th[3]);
        float c4 = __cosf(hi.x + th[4]);
        float c5 = __cosf(hi.y + th[5]);
        float c6 = __cosf(hi.z + th[6]);
        float c7 = __cosf(hi.w + th[7]);
        float m1 = c0 * c1;
        float m2 = m1 * c2;
        float m0 = ((c1 * c2) * (c3 * c4)) * ((c5 * c6) * c7);
        float q0 = m0 * 0.125f, q1 = m1 * 0.125f, q2 = m2 * 0.125f;

        float sum = 0.f, a0 = 0.f, a1 = 0.f;
#pragma unroll 4
        for (int t = 0; t < NS; ++t) {
            float2 kk = __half22float2(kvA[h][t]);
            float2 kv = __half22float2(kvB[h][t]);
            float v1 = __half2float(kvC[h][t]);
            float sc = q0 * kk.x + q1 * kk.y + q2 * kv.x;
            float e = __expf(sc);
            sum += e;
            a0 += e * kv.y;
            a1 += e * v1;
        }
        float inv = 1.0f / sum;
        attl[sl][h * 2] = a0 * inv;
        attl[sl][h * 2 + 1] = a1 * inv;
    }
    __syncthreads();

    {
        const int e = tid & 63;
        const int rr = tid >> 6;
#pragma unroll
        for (int i = 0; i < 8; ++i) {
            int sl = rr * 8 + i;
            float acc = bl[e];
#pragma unroll
            for (int j = 0; j < 16; ++j)
                acc += attl[sl][j] * Wt[j][e];
            int sg = chunk * SPB + sl;
            out[(((size_t)(b * NS + sg)) << 6) + e] = acc;
        }
    }
}

extern "C" void kernel_launch(void* const* d_in, const int* in_sizes, int n_in,
                              void* d_out, int out_size, void* d_ws, size_t ws_size,
                              hipStream_t stream) {
    const float* x     = (const float*)d_in[0];
    const float* theta = (const float*)d_in[1];
    const float* W     = (const float*)d_in[2];
    const float* bias  = (const float*)d_in[3];
    float* out = (float*)d_out;

    if (ws_size >= (size_t)WS_FLOATS * sizeof(float)) {
        float*  wsf = (float*)d_ws;
        float4* q4  = (float4*)wsf + Q4_OFF;
        float4* kv4 = (float4*)wsf + KV4_OFF;
        float*  v1  = wsf + V1_OFF;
        float*  att = wsf + ATT_OFF;

        meas_kernel<<<dim3(NB * NS * NH / 256), dim3(256), 0, stream>>>(x, theta, q4, kv4, v1);
        attn_kernel<<<dim3(NB * NH * (NS / SPB)), dim3(256), 0, stream>>>(q4, kv4, v1, att);
        proj_kernel<<<dim3(NB * NS / 4), dim3(256), 0, stream>>>(att, W, bias, out);
    } else {
        fused_kernel<<<dim3(NB * (NS / SPB)), dim3(256), 0, stream>>>(x, theta, W, bias, out);
    }
}